// Round 13
// baseline (453.024 us; speedup 1.0000x reference)
//
#include <hip/hip_runtime.h>
#include <hip/hip_bf16.h>

using bf16 = __hip_bfloat16;
typedef __attribute__((ext_vector_type(8))) short bf16x8;
typedef __attribute__((ext_vector_type(8))) unsigned short u16x8;
typedef __attribute__((ext_vector_type(4))) float f32x4;

constexpr int BATCH = 4096;
constexpr int D_IN  = 1024;
constexpr int NEXP  = 16;
constexpr int EMB   = 256;
constexpr int H1    = 2048;
constexpr int H2    = 1024;
constexpr int OUTD  = 512;
constexpr int SLOTS = BATCH * 2;
constexpr int SLOTS_PAD = SLOTS + 256;
constexpr int MAX_T256 = SLOTS / 256 + NEXP;  // 48 = 8 bins x 6
constexpr int MAX_T128 = SLOTS / 128 + NEXP;  // 80 = 8 bins x 10
constexpr int K3    = 3 * D_IN;

// ---- workspace layout (bytes) ----
constexpr size_t WS_XB     = 0;
constexpr size_t WS_XLO    = WS_XB     + (size_t)BATCH * D_IN * 2;
constexpr size_t WS_H1     = WS_XLO    + (size_t)BATCH * D_IN * 2;
constexpr size_t WS_H2     = WS_H1     + (size_t)SLOTS_PAD * H1 * 2;
constexpr size_t WS_OSL    = WS_H2     + (size_t)SLOTS_PAD * H2 * 2;
constexpr size_t WS_TOPI   = WS_OSL    + (size_t)SLOTS_PAD * OUTD * 4;
constexpr size_t WS_GATES  = WS_TOPI   + (size_t)SLOTS * 4;
constexpr size_t WS_SLOTOF = WS_GATES  + (size_t)SLOTS * 4;
constexpr size_t WS_TOKL   = WS_SLOTOF + (size_t)SLOTS * 4;
constexpr size_t WS_CNT    = WS_TOKL   + (size_t)SLOTS_PAD * 4;
constexpr size_t WS_TMAP256= WS_CNT    + 64 * 4;
constexpr size_t WS_TMAP128= WS_TMAP256+ (size_t)MAX_T256 * 8;
constexpr size_t WS_WR3    = ((WS_TMAP128 + (size_t)MAX_T128 * 8) + 255) & ~(size_t)255;
constexpr size_t WS_WT     = ((WS_WR3 + (size_t)EMB * K3 * 2) + 255) & ~(size_t)255;
constexpr size_t WT_BYTES  = (size_t)NEXP * H1 * D_IN * 2;   // 67.1 MB
constexpr size_t WS_WTB    = WS_WT + WT_BYTES;
constexpr size_t NEED2     = WS_WTB + WT_BYTES;              // ~222 MB (r10: satisfied)

__device__ __forceinline__ unsigned short f2bf(float f) {
    bf16 h = __float2bfloat16(f);
    return __builtin_bit_cast(unsigned short, h);
}
__device__ __forceinline__ float bf2f(unsigned short h) {
    return __builtin_bit_cast(float, (unsigned)h << 16);
}

__device__ __forceinline__ void gload16(const unsigned short* g, unsigned short* l) {
    __builtin_amdgcn_global_load_lds(
        (const __attribute__((address_space(1))) unsigned int*)g,
        (__attribute__((address_space(3))) unsigned int*)l, 16, 0, 0);
}

template <int N>
__device__ __forceinline__ void waitcnt_vm() {
    static_assert(N == 0 || N == 4 || N == 8, "add case");
    if constexpr (N == 0) asm volatile("s_waitcnt vmcnt(0)" ::: "memory");
    else if constexpr (N == 4) asm volatile("s_waitcnt vmcnt(4)" ::: "memory");
    else if constexpr (N == 8) asm volatile("s_waitcnt vmcnt(8)" ::: "memory");
}

// ---------------- wtrans device body: W[e][k][n] f32 -> Wt[e][n][k] bf16 ----------------
__device__ __forceinline__ void wtrans_body(const float* __restrict__ W,
                                            unsigned short* __restrict__ Wt,
                                            int KD, int ND, int e, int k0, int n0,
                                            char* smem) {
    float* Tf = (float*)smem;   // [64][65]
    int t  = threadIdx.x;
    int kr = t >> 4, c4 = (t & 15) * 4;
    const float* Wb = W + ((size_t)e * KD + k0) * ND + n0;
#pragma unroll
    for (int i = 0; i < 4; i++) {
        float4 v = *reinterpret_cast<const float4*>(Wb + (size_t)(kr + i * 16) * ND + c4);
        Tf[(kr + i * 16) * 65 + c4 + 0] = v.x; Tf[(kr + i * 16) * 65 + c4 + 1] = v.y;
        Tf[(kr + i * 16) * 65 + c4 + 2] = v.z; Tf[(kr + i * 16) * 65 + c4 + 3] = v.w;
    }
    __syncthreads();
    unsigned short* Wtb = Wt + ((size_t)e * ND + n0) * KD + k0;
#pragma unroll
    for (int i = 0; i < 2; i++) {
        int idx = t + i * 256;
        int n = idx >> 3, ck = (idx & 7) * 8;
        u16x8 o;
#pragma unroll
        for (int j = 0; j < 8; j++) o[j] = f2bf(Tf[(ck + j) * 65 + n]);
        *reinterpret_cast<u16x8*>(Wtb + (size_t)n * KD + ck) = o;
    }
}

// ---------------- prep: x->bf16 hi/lo | Wr->Wrt3 | zero counts (r10-proven) ----------------
__global__ __launch_bounds__(256) void k_prep(const float* __restrict__ x,
                                              unsigned short* __restrict__ xhi,
                                              unsigned short* __restrict__ xlo,
                                              const float* __restrict__ Wr,
                                              unsigned short* __restrict__ Wrt3,
                                              int* __restrict__ counts) {
    __shared__ float Tf[64][65];
    int bx = blockIdx.x, t = threadIdx.x;
    if (bx < 4096) {
        int i = bx * 256 + t;
        float4 v = reinterpret_cast<const float4*>(x)[i];
        ushort4 h, l;
        h.x = f2bf(v.x); h.y = f2bf(v.y); h.z = f2bf(v.z); h.w = f2bf(v.w);
        l.x = f2bf(v.x - bf2f(h.x)); l.y = f2bf(v.y - bf2f(h.y));
        l.z = f2bf(v.z - bf2f(h.z)); l.w = f2bf(v.w - bf2f(h.w));
        reinterpret_cast<ushort4*>(xhi)[i] = h;
        reinterpret_cast<ushort4*>(xlo)[i] = l;
    } else if (bx < 4160) {
        int idx = bx - 4096;
        int n0 = (idx & 3) * 64, k0 = (idx >> 2) * 64;
        const float* Wb = Wr + (size_t)k0 * EMB + n0;
        int kr = t >> 4, c4 = (t & 15) * 4;
#pragma unroll
        for (int i = 0; i < 4; i++) {
            float4 v = *reinterpret_cast<const float4*>(Wb + (size_t)(kr + i * 16) * EMB + c4);
            Tf[kr + i * 16][c4 + 0] = v.x; Tf[kr + i * 16][c4 + 1] = v.y;
            Tf[kr + i * 16][c4 + 2] = v.z; Tf[kr + i * 16][c4 + 3] = v.w;
        }
        __syncthreads();
#pragma unroll
        for (int i = 0; i < 2; i++) {
            int idx2 = t + i * 256;
            int n = idx2 >> 3, ck = (idx2 & 7) * 8;
            u16x8 hi, lo;
#pragma unroll
            for (int j = 0; j < 8; j++) {
                float w = Tf[ck + j][n];
                unsigned short h = f2bf(w);
                hi[j] = h; lo[j] = f2bf(w - bf2f(h));
            }
            unsigned short* dst = Wrt3 + (size_t)(n0 + n) * K3 + k0 + ck;
            *reinterpret_cast<u16x8*>(dst)            = hi;
            *reinterpret_cast<u16x8*>(dst + D_IN)     = hi;
            *reinterpret_cast<u16x8*>(dst + 2 * D_IN) = lo;
        }
    } else {
        if (t < 16) counts[t] = 0;
    }
}

// ---------------- router3 (bf16x3, 2-deep T4) + fused wtrans(W1)+wtrans(W2) ----------------
// Router blocks (256) dispatch first; wtrans blocks backfill + soak the idle
// bandwidth of this latency-bound phase. GEMM branch anchors the register
// budget (r11 lesson: never pair wtrans with a LIGHT-register kernel).
__global__ __launch_bounds__(256) void k_router_wt(const unsigned short* __restrict__ xhi,
                                                   const unsigned short* __restrict__ xlo,
                                                   const unsigned short* __restrict__ wrt3,
                                                   const float* __restrict__ br,
                                                   float* __restrict__ qout,
                                                   const float* __restrict__ W1,
                                                   unsigned short* __restrict__ wt1,
                                                   const float* __restrict__ W2,
                                                   unsigned short* __restrict__ wt2) {
    __shared__ __align__(16) char smem[32768];
    int bx = blockIdx.x;
    if (bx >= 256) {
        int idx = bx - 256;
        if (idx < 8192) {          // W1: 16 kblk x 32 nblk x 16 e
            int e = idx >> 9, rem = idx & 511;
            wtrans_body(W1, wt1, D_IN, H1, e, (rem >> 5) << 6, (rem & 31) << 6, smem);
        } else {                   // W2: 32 kblk x 16 nblk x 16 e
            int i2 = idx - 8192;
            int e = i2 >> 9, rem = i2 & 511;
            wtrans_body(W2, wt2, H1, H2, e, (rem >> 4) << 6, (rem & 15) << 6, smem);
        }
        return;
    }
    unsigned short* As = (unsigned short*)smem;      // [2][4096]
    unsigned short* Bs = As + 8192;
    int nb = (bx & 3) * 64;
    int mb = (bx >> 2) * 64;

    int t    = threadIdx.x;
    int lane = t & 63;
    int w    = t >> 6;
    int wr   = (w >> 1) * 32;
    int wc   = (w & 1) * 32;

    int srow = t >> 3;
    int swz  = (t & 7) ^ (srow & 7);
    size_t aoff[2], boff[2];
#pragma unroll
    for (int i = 0; i < 2; i++) {
        int row = i * 32 + srow;
        aoff[i] = (size_t)(mb + row) * D_IN + swz * 8;
        boff[i] = (size_t)(nb + row) * K3 + swz * 8;
    }

    auto STAGE = [&](int buf, int tts) {
        const unsigned short* abase = (tts >= 16 && tts < 32) ? xlo : xhi;
        int kk = (tts & 15) * 64;
#pragma unroll
        for (int i = 0; i < 2; i++) {
            gload16(abase + aoff[i] + kk, As + buf * 4096 + (i * 32 + w * 8) * 64 + lane * 8);
            gload16(wrt3 + boff[i] + tts * 64, Bs + buf * 4096 + (i * 32 + w * 8) * 64 + lane * 8);
        }
    };

    f32x4 acc[2][2];
#pragma unroll
    for (int mi = 0; mi < 2; mi++)
#pragma unroll
        for (int ni = 0; ni < 2; ni++) acc[mi][ni] = {0.f, 0.f, 0.f, 0.f};

    int lr  = lane & 15;
    int lkc = lane >> 4;

    constexpr int NT = K3 / 64;
    STAGE(0, 0);
    STAGE(1, 1);

    for (int tt = 0; tt < NT; tt++) {
        int cur = tt & 1;
        if (tt + 1 < NT) waitcnt_vm<4>(); else waitcnt_vm<0>();
        __builtin_amdgcn_s_barrier();
        const char* Ab = (const char*)(As + cur * 4096);
        const char* Bb = (const char*)(Bs + cur * 4096);
#pragma unroll
        for (int ks = 0; ks < 2; ks++) {
            bf16x8 a[2], b[2];
#pragma unroll
            for (int mi = 0; mi < 2; mi++) {
                int row = wr + mi * 16 + lr;
                int c   = (lkc + ks * 4) ^ (row & 7);
                a[mi] = *reinterpret_cast<const bf16x8*>(Ab + row * 128 + c * 16);
            }
#pragma unroll
            for (int ni = 0; ni < 2; ni++) {
                int row = wc + ni * 16 + lr;
                int c   = (lkc + ks * 4) ^ (row & 7);
                b[ni] = *reinterpret_cast<const bf16x8*>(Bb + row * 128 + c * 16);
            }
#pragma unroll
            for (int mi = 0; mi < 2; mi++)
#pragma unroll
                for (int ni = 0; ni < 2; ni++)
                    acc[mi][ni] = __builtin_amdgcn_mfma_f32_16x16x32_bf16(a[mi], b[ni], acc[mi][ni], 0, 0, 0);
        }
        __builtin_amdgcn_s_barrier();
        if (tt + 2 < NT) STAGE(cur, tt + 2);
    }

    int rowbase = (lane >> 4) * 4;
#pragma unroll
    for (int ni = 0; ni < 2; ni++) {
        int col = nb + wc + ni * 16 + lr;
        float bv = br[col];
#pragma unroll
        for (int mi = 0; mi < 2; mi++) {
#pragma unroll
            for (int qi = 0; qi < 4; qi++) {
                int row = mb + wr + mi * 16 + rowbase + qi;
                qout[(size_t)row * EMB + col] = acc[mi][ni][qi] + bv;
            }
        }
    }
}

// ---------------- topk + count (PURE - r11 lesson; r10-proven body) ----------------
__global__ __launch_bounds__(256) void k_topk_count(const float* __restrict__ q,
                                                    const float* __restrict__ emb,
                                                    float* __restrict__ gp,
                                                    int* __restrict__ topi,
                                                    float* __restrict__ gates,
                                                    int* __restrict__ counts) {
    int b    = blockIdx.x * 4 + (threadIdx.x >> 6);
    int lane = threadIdx.x & 63;
    int e    = lane & 15;
    int seg  = (lane >> 4) * 64;
    const float* qr = q + (size_t)b * EMB + seg;
    const float* er = emb + (size_t)e * EMB + seg;
    float d2 = 0.f;
#pragma unroll 8
    for (int i = 0; i < 64; i++) { float d = qr[i] - er[i]; d2 = fmaf(d, d, d2); }
    d2 += __shfl_xor(d2, 16);
    d2 += __shfl_xor(d2, 32);
    float s = -d2;
    float m = s;
#pragma unroll
    for (int o = 1; o < 16; o <<= 1) m = fmaxf(m, __shfl_xor(m, o));
    float ex  = __expf(s - m);
    float sum = ex;
#pragma unroll
    for (int o = 1; o < 16; o <<= 1) sum += __shfl_xor(sum, o);
    if (lane < 16) gp[(size_t)b * NEXP + lane] = ex / sum;
    float v1 = s; int i1 = e;
#pragma unroll
    for (int o = 1; o < 16; o <<= 1) {
        float ov = __shfl_xor(v1, o); int oi = __shfl_xor(i1, o);
        if (ov > v1 || (ov == v1 && oi < i1)) { v1 = ov; i1 = oi; }
    }
    float s2 = (e == i1) ? -1e30f : s;
    float v2 = s2; int i2 = e;
#pragma unroll
    for (int o = 1; o < 16; o <<= 1) {
        float ov = __shfl_xor(v2, o); int oi = __shfl_xor(i2, o);
        if (ov > v2 || (ov == v2 && oi < i2)) { v2 = ov; i2 = oi; }
    }
    if (lane == 0) {
        topi[b * 2] = i1; topi[b * 2 + 1] = i2;
        float tv  = __expf(v2 - v1);
        float inv = 1.f / (1.f + tv);
        gates[b * 2] = inv; gates[b * 2 + 1] = tv * inv;
        atomicAdd(&counts[i1], 1);
        atomicAdd(&counts[i2], 1);
    }
}

// ---------------- scan: offsets + XCD bin-packed tilemaps (r12-proven) ----------------
__global__ void k_scan(const int* __restrict__ counts, int* __restrict__ offsets,
                       int* __restrict__ cursors, int2* __restrict__ tmap256,
                       int2* __restrict__ tmap128) {
    if (threadIdx.x != 0) return;
    int off = 0;
    for (int e = 0; e < NEXP; e++) {
        offsets[e] = off; cursors[e] = off;
        off += counts[e];
    }
    for (int i = 0; i < MAX_T256; i++) tmap256[i] = make_int2(-1, 0);
    for (int i = 0; i < MAX_T128; i++) tmap128[i] = make_int2(-1, 0);
    {
        int binload[8] = {0, 0, 0, 0, 0, 0, 0, 0};
        for (int e = 0; e < NEXP; e++) {
            int rem = (counts[e] + 255) >> 8, ti = 0;
            while (rem > 0) {
                int b = 0;
                for (int q2 = 1; q2 < 8; q2++)
                    if (binload[q2] < binload[b]) b = q2;
                int space = 6 - binload[b];
                if (space <= 0) break;
                int take = (rem < space) ? rem : space;
                for (int i = 0; i < take; i++)
                    tmap256[b * 6 + binload[b] + i] = make_int2(e, (ti + i) * 256);
                binload[b] += take; ti += take; rem -= take;
            }
        }
    }
    {
        int binload[8] = {0, 0, 0, 0, 0, 0, 0, 0};
        for (int e = 0; e < NEXP; e++) {
            int rem = (counts[e] + 127) >> 7, ti = 0;
            while (rem > 0) {
                int b = 0;
                for (int q2 = 1; q2 < 8; q2++)
                    if (binload[q2] < binload[b]) b = q2;
                int space = 10 - binload[b];
                if (space <= 0) break;
                int take = (rem < space) ? rem : space;
                for (int i = 0; i < take; i++)
                    tmap128[b * 10 + binload[b] + i] = make_int2(e, (ti + i) * 128);
                binload[b] += take; ti += take; rem -= take;
            }
        }
    }
}

__global__ __launch_bounds__(256) void k_scatter(const int* __restrict__ topi, int* __restrict__ cursors,
                                                 int* __restrict__ toklist, int* __restrict__ slotof) {
    int i = blockIdx.x * 256 + threadIdx.x;
    int e = topi[i];
    int s = atomicAdd(&cursors[e], 1);
    toklist[s] = i >> 1;
    slotof[i]  = s;
}

// ---------------- standalone wtrans (W3 always; W1/W2 in fallback tier) ----------------
__global__ __launch_bounds__(256) void k_wtrans(const float* __restrict__ W,
                                                unsigned short* __restrict__ Wt,
                                                int KD, int ND) {
    __shared__ __align__(16) char smem[64 * 65 * 4];
    wtrans_body(W, Wt, KD, ND, blockIdx.z, blockIdx.y * 64, blockIdx.x * 64, smem);
}

// ---------------- grouped expert GEMM (r7 body + r12 XCD bin mapping) ----------------
template <int KD, int ND, int BM, int BN, int WM, int WN, int MODE, int MINW, int CAP>
__global__ __launch_bounds__(WM * WN * 64, MINW) void k_gemm(
    const unsigned short* __restrict__ Xin, const unsigned short* __restrict__ Wt,
    const float* __restrict__ bg, unsigned short* __restrict__ Hout,
    float* __restrict__ Oout, const int* __restrict__ counts,
    const int* __restrict__ offsets, const int* __restrict__ toklist,
    const int2* __restrict__ tmap) {
    constexpr int THREADS = WM * WN * 64;
    constexpr int FM = BM / (WM * 16);
    constexpr int FN = BN / (WN * 16);
    constexpr int A_ISS = BM * 8 / THREADS;
    constexpr int B_ISS = BN * 8 / THREADS;
    constexpr int RPI = THREADS / 8;
    constexpr int SL  = A_ISS + B_ISS;

    int id  = blockIdx.x;
    int bin = id & 7;
    int j   = id >> 3;
    int y   = bin * CAP + j % CAP;
    int xnb = j / CAP;

    int2 tm = tmap[y];
    int e = tm.x;
    if (e < 0) return;
    int base = tm.y;
    int n_e  = counts[e];
    int off  = offsets[e];
    int n0   = xnb * BN;

    __shared__ __align__(16) unsigned short As[2][BM * 64];
    __shared__ __align__(16) unsigned short Bs[2][BN * 64];

    int t    = threadIdx.x;
    int lane = t & 63;
    int w    = t >> 6;
    int wm   = w / WN;
    int wn   = w % WN;

    int srow  = t >> 3;
    int chunk = t & 7;
    const unsigned short* asrc[A_ISS];
    const unsigned short* bsrc[B_ISS];
#pragma unroll
    for (int i = 0; i < A_ISS; i++) {
        int row = i * RPI + srow;
        int swz = chunk ^ (row & 7);
        int g   = base + row;
        size_t arow;
        if (MODE == 0) {
            int gg = (g < n_e) ? g : (n_e - 1);
            arow = (size_t)toklist[off + gg];
        } else {
            arow = (size_t)(off + g);
        }
        asrc[i] = Xin + arow * KD + swz * 8;
    }
#pragma unroll
    for (int i = 0; i < B_ISS; i++) {
        int row = i * RPI + srow;
        int swz = chunk ^ (row & 7);
        bsrc[i] = Wt + ((size_t)e * ND + n0 + row) * KD + swz * 8;
    }

    auto STAGE = [&](int buf, int kt) {
#pragma unroll
        for (int i = 0; i < A_ISS; i++)
            gload16(asrc[i] + kt, &As[buf][(i * RPI + w * 8) * 64] + lane * 8);
#pragma unroll
        for (int i = 0; i < B_ISS; i++)
            gload16(bsrc[i] + kt, &Bs[buf][(i * RPI + w * 8) * 64] + lane * 8);
    };

    f32x4 acc[FM][FN];
#pragma unroll
    for (int mi = 0; mi < FM; mi++)
#pragma unroll
        for (int ni = 0; ni < FN; ni++) acc[mi][ni] = {0.f, 0.f, 0.f, 0.f};

    int lr  = lane & 15;
    int lkc = lane >> 4;

    constexpr int NT = KD / 64;
    STAGE(0, 0);
    STAGE(1, 64);

    for (int tt = 0; tt < NT; tt++) {
        int cur = tt & 1;
        if (tt + 1 < NT) waitcnt_vm<SL>(); else waitcnt_vm<0>();
        __builtin_amdgcn_s_barrier();
        const char* Ab = (const char*)As[cur];
        const char* Bb = (const char*)Bs[cur];
#pragma unroll
        for (int ks = 0; ks < 2; ks++) {
            bf16x8 b[FN];
#pragma unroll
            for (int ni = 0; ni < FN; ni++) {
                int row = wn * (BN / WN) + ni * 16 + lr;
                int c   = (lkc + ks * 4) ^ (row & 7);
                b[ni] = *reinterpret_cast<const bf16x8*>(Bb + row * 128 + c * 16);
            }
            bf16x8 a[FM];
#pragma unroll
            for (int mi = 0; mi < FM; mi++) {
                int row = wm * (BM / WM) + mi * 16 + lr;
                int c   = (lkc + ks * 4) ^ (row & 7);
                a[mi] = *reinterpret_cast<const bf16x8*>(Ab + row * 128 + c * 16);
            }
#pragma unroll
            for (int mi = 0; mi < FM; mi++)
#pragma unroll
                for (int ni = 0; ni < FN; ni++)
                    acc[mi][ni] = __builtin_amdgcn_mfma_f32_16x16x32_bf16(a[mi], b[ni], acc[mi][ni], 0, 0, 0);
        }
        __builtin_amdgcn_s_barrier();
        if (tt + 2 < NT) STAGE(cur, (tt + 2) * 64);
    }

    int rowbase = (lane >> 4) * 4;
#pragma unroll
    for (int ni = 0; ni < FN; ni++) {
        int col = n0 + wn * (BN / WN) + ni * 16 + lr;
        float bv = bg[(size_t)e * ND + col];
#pragma unroll
        for (int mi = 0; mi < FM; mi++) {
#pragma unroll
            for (int qi = 0; qi < 4; qi++) {
                int g = base + wm * (BM / WM) + mi * 16 + rowbase + qi;
                if (g < n_e) {
                    float v = acc[mi][ni][qi] + bv;
                    if (MODE == 2) {
                        Oout[(size_t)(off + g) * ND + col] = v;
                    } else {
                        v = fmaxf(v, 0.f);
                        Hout[(size_t)(off + g) * ND + col] = f2bf(v);
                    }
                }
            }
        }
    }
}

// ---------------- final combine ----------------
__global__ __launch_bounds__(128) void k_combine(const float* __restrict__ osl,
                                                 const float* __restrict__ gates,
                                                 const int* __restrict__ slotof,
                                                 float* __restrict__ outf) {
    int b = blockIdx.x;
    int j = threadIdx.x;
    int s0 = slotof[b * 2], s1 = slotof[b * 2 + 1];
    float g0 = gates[b * 2], g1 = gates[b * 2 + 1];
    float4 o0 = reinterpret_cast<const float4*>(osl + (size_t)s0 * OUTD)[j];
    float4 o1 = reinterpret_cast<const float4*>(osl + (size_t)s1 * OUTD)[j];
    float4 r;
    r.x = g0 * o0.x + g1 * o1.x;
    r.y = g0 * o0.y + g1 * o1.y;
    r.z = g0 * o0.z + g1 * o1.z;
    r.w = g0 * o0.w + g1 * o1.w;
    reinterpret_cast<float4*>(outf + (size_t)b * OUTD)[j] = r;
}

extern "C" void kernel_launch(void* const* d_in, const int* in_sizes, int n_in,
                              void* d_out, int out_size, void* d_ws, size_t ws_size,
                              hipStream_t stream) {
    const float* x   = (const float*)d_in[0];
    const float* Wr  = (const float*)d_in[1];
    const float* br  = (const float*)d_in[2];
    const float* emb = (const float*)d_in[3];
    const float* W1  = (const float*)d_in[4];
    const float* b1  = (const float*)d_in[5];
    const float* W2  = (const float*)d_in[6];
    const float* b2  = (const float*)d_in[7];
    const float* W3  = (const float*)d_in[8];
    const float* b3  = (const float*)d_in[9];

    float* out_final = (float*)d_out;
    float* out_q     = out_final + (size_t)BATCH * OUTD;
    float* out_gp    = out_q + (size_t)BATCH * EMB;

    char* ws = (char*)d_ws;
    unsigned short* xb  = (unsigned short*)(ws + WS_XB);
    unsigned short* xlo = (unsigned short*)(ws + WS_XLO);
    unsigned short* h1  = (unsigned short*)(ws + WS_H1);
    unsigned short* h2  = (unsigned short*)(ws + WS_H2);
    float* osl    = (float*)(ws + WS_OSL);
    int*   topi   = (int*)(ws + WS_TOPI);
    float* gates  = (float*)(ws + WS_GATES);
    int*   slotof = (int*)(ws + WS_SLOTOF);
    int*   toklist= (int*)(ws + WS_TOKL);
    int*   counts = (int*)(ws + WS_CNT);
    int*   offsets= counts + 16;
    int*   cursors= counts + 32;
    int2*  tmap256= (int2*)(ws + WS_TMAP256);
    int2*  tmap128= (int2*)(ws + WS_TMAP128);
    unsigned short* wrt3 = (unsigned short*)(ws + WS_WR3);
    unsigned short* wtA  = (unsigned short*)(ws + WS_WT);
    unsigned short* wtB  = (unsigned short*)(ws + WS_WTB);

    const bool t2 = (ws_size >= NEED2);

    k_prep<<<4161, 256, 0, stream>>>(x, xb, xlo, Wr, wrt3, counts);

    if (t2) {
        k_router_wt<<<256 + 8192 + 8192, 256, 0, stream>>>(
            xb, xlo, wrt3, br, out_q, W1, wtA, W2, wtB);
    } else {
        k_router_wt<<<256, 256, 0, stream>>>(
            xb, xlo, wrt3, br, out_q, nullptr, nullptr, nullptr, nullptr);
    }

    k_topk_count<<<BATCH / 4, 256, 0, stream>>>(out_q, emb, out_gp, topi, gates, counts);
    k_scan<<<1, 64, 0, stream>>>(counts, offsets, cursors, tmap256, tmap128);
    k_scatter<<<SLOTS / 256, 256, 0, stream>>>(topi, cursors, toklist, slotof);

    if (!t2) k_wtrans<<<dim3(H1 / 64, D_IN / 64, NEXP), 256, 0, stream>>>(W1, wtA, D_IN, H1);
    k_gemm<D_IN, H1, 256, 256, 2, 4, 0, 1, 6><<<(H1 / 256) * 48, 512, 0, stream>>>(
        xb, wtA, b1, h1, nullptr, counts, offsets, toklist, tmap256);

    if (!t2) k_wtrans<<<dim3(H2 / 64, H1 / 64, NEXP), 256, 0, stream>>>(W2, wtA, H1, H2);
    k_gemm<H1, H2, 256, 256, 2, 4, 1, 1, 6><<<(H2 / 256) * 48, 512, 0, stream>>>(
        h1, t2 ? wtB : wtA, b2, h2, nullptr, counts, offsets, toklist, tmap256);

    k_wtrans<<<dim3(OUTD / 64, H2 / 64, NEXP), 256, 0, stream>>>(W3, wtA, H2, OUTD);
    k_gemm<H2, OUTD, 128, 128, 2, 2, 2, 2, 10><<<(OUTD / 128) * 80, 256, 0, stream>>>(
        h2, wtA, b3, nullptr, osl, counts, offsets, toklist, tmap128);

    k_combine<<<BATCH, 128, 0, stream>>>(osl, gates, slotof, out_final);
}

// Round 14
// 383.861 us; speedup vs baseline: 1.1802x; 1.1802x over previous
//
#include <hip/hip_runtime.h>
#include <hip/hip_bf16.h>

using bf16 = __hip_bfloat16;
typedef __attribute__((ext_vector_type(8))) short bf16x8;
typedef __attribute__((ext_vector_type(8))) unsigned short u16x8;
typedef __attribute__((ext_vector_type(4))) float f32x4;

constexpr int BATCH = 4096;
constexpr int D_IN  = 1024;
constexpr int NEXP  = 16;
constexpr int EMB   = 256;
constexpr int H1    = 2048;
constexpr int H2    = 1024;
constexpr int OUTD  = 512;
constexpr int SLOTS = BATCH * 2;
constexpr int SLOTS_PAD = SLOTS + 256;
constexpr int MAX_T256 = SLOTS / 256 + NEXP;  // 48 = 8 bins x 6
constexpr int MAX_T128 = SLOTS / 128 + NEXP;  // 80 = 8 bins x 10
constexpr int K3    = 3 * D_IN;

// ---- workspace layout (bytes) ----
constexpr size_t WS_XB     = 0;
constexpr size_t WS_XLO    = WS_XB     + (size_t)BATCH * D_IN * 2;
constexpr size_t WS_H1     = WS_XLO    + (size_t)BATCH * D_IN * 2;
constexpr size_t WS_H2     = WS_H1     + (size_t)SLOTS_PAD * H1 * 2;
constexpr size_t WS_OSL    = WS_H2     + (size_t)SLOTS_PAD * H2 * 2;
constexpr size_t WS_TOPI   = WS_OSL    + (size_t)SLOTS_PAD * OUTD * 4;
constexpr size_t WS_GATES  = WS_TOPI   + (size_t)SLOTS * 4;
constexpr size_t WS_SLOTOF = WS_GATES  + (size_t)SLOTS * 4;
constexpr size_t WS_TOKL   = WS_SLOTOF + (size_t)SLOTS * 4;
constexpr size_t WS_CNT    = WS_TOKL   + (size_t)SLOTS_PAD * 4;
constexpr size_t WS_TMAP256= WS_CNT    + 64 * 4;
constexpr size_t WS_TMAP128= WS_TMAP256+ (size_t)MAX_T256 * 8;
constexpr size_t WS_WR3    = ((WS_TMAP128 + (size_t)MAX_T128 * 8) + 255) & ~(size_t)255;
constexpr size_t WS_WT     = ((WS_WR3 + (size_t)EMB * K3 * 2) + 255) & ~(size_t)255;
constexpr size_t WT_BYTES  = (size_t)NEXP * H1 * D_IN * 2;   // 67.1 MB
constexpr size_t WS_WTB    = WS_WT + WT_BYTES;
constexpr size_t NEED2     = WS_WTB + WT_BYTES;              // ~222 MB (r10: satisfied)

__device__ __forceinline__ unsigned short f2bf(float f) {
    bf16 h = __float2bfloat16(f);
    return __builtin_bit_cast(unsigned short, h);
}
__device__ __forceinline__ float bf2f(unsigned short h) {
    return __builtin_bit_cast(float, (unsigned)h << 16);
}

__device__ __forceinline__ void gload16(const unsigned short* g, unsigned short* l) {
    __builtin_amdgcn_global_load_lds(
        (const __attribute__((address_space(1))) unsigned int*)g,
        (__attribute__((address_space(3))) unsigned int*)l, 16, 0, 0);
}

template <int N>
__device__ __forceinline__ void waitcnt_vm() {
    static_assert(N == 0 || N == 4 || N == 8, "add case");
    if constexpr (N == 0) asm volatile("s_waitcnt vmcnt(0)" ::: "memory");
    else if constexpr (N == 4) asm volatile("s_waitcnt vmcnt(4)" ::: "memory");
    else if constexpr (N == 8) asm volatile("s_waitcnt vmcnt(8)" ::: "memory");
}

// ---------------- wtrans device body: W[e][k][n] f32 -> Wt[e][n][k] bf16 ----------------
__device__ __forceinline__ void wtrans_body(const float* __restrict__ W,
                                            unsigned short* __restrict__ Wt,
                                            int KD, int ND, int e, int k0, int n0,
                                            char* smem) {
    float* Tf = (float*)smem;   // [64][65]
    int t  = threadIdx.x;
    int kr = t >> 4, c4 = (t & 15) * 4;
    const float* Wb = W + ((size_t)e * KD + k0) * ND + n0;
#pragma unroll
    for (int i = 0; i < 4; i++) {
        float4 v = *reinterpret_cast<const float4*>(Wb + (size_t)(kr + i * 16) * ND + c4);
        Tf[(kr + i * 16) * 65 + c4 + 0] = v.x; Tf[(kr + i * 16) * 65 + c4 + 1] = v.y;
        Tf[(kr + i * 16) * 65 + c4 + 2] = v.z; Tf[(kr + i * 16) * 65 + c4 + 3] = v.w;
    }
    __syncthreads();
    unsigned short* Wtb = Wt + ((size_t)e * ND + n0) * KD + k0;
#pragma unroll
    for (int i = 0; i < 2; i++) {
        int idx = t + i * 256;
        int n = idx >> 3, ck = (idx & 7) * 8;
        u16x8 o;
#pragma unroll
        for (int j = 0; j < 8; j++) o[j] = f2bf(Tf[(ck + j) * 65 + n]);
        *reinterpret_cast<u16x8*>(Wtb + (size_t)n * KD + ck) = o;
    }
}

// ---------------- prep: x->bf16 hi/lo | Wr->Wrt3 | zero counts ----------------
__global__ __launch_bounds__(256) void k_prep(const float* __restrict__ x,
                                              unsigned short* __restrict__ xhi,
                                              unsigned short* __restrict__ xlo,
                                              const float* __restrict__ Wr,
                                              unsigned short* __restrict__ Wrt3,
                                              int* __restrict__ counts) {
    __shared__ float Tf[64][65];
    int bx = blockIdx.x, t = threadIdx.x;
    if (bx < 4096) {
        int i = bx * 256 + t;
        float4 v = reinterpret_cast<const float4*>(x)[i];
        ushort4 h, l;
        h.x = f2bf(v.x); h.y = f2bf(v.y); h.z = f2bf(v.z); h.w = f2bf(v.w);
        l.x = f2bf(v.x - bf2f(h.x)); l.y = f2bf(v.y - bf2f(h.y));
        l.z = f2bf(v.z - bf2f(h.z)); l.w = f2bf(v.w - bf2f(h.w));
        reinterpret_cast<ushort4*>(xhi)[i] = h;
        reinterpret_cast<ushort4*>(xlo)[i] = l;
    } else if (bx < 4160) {
        int idx = bx - 4096;
        int n0 = (idx & 3) * 64, k0 = (idx >> 2) * 64;
        const float* Wb = Wr + (size_t)k0 * EMB + n0;
        int kr = t >> 4, c4 = (t & 15) * 4;
#pragma unroll
        for (int i = 0; i < 4; i++) {
            float4 v = *reinterpret_cast<const float4*>(Wb + (size_t)(kr + i * 16) * EMB + c4);
            Tf[kr + i * 16][c4 + 0] = v.x; Tf[kr + i * 16][c4 + 1] = v.y;
            Tf[kr + i * 16][c4 + 2] = v.z; Tf[kr + i * 16][c4 + 3] = v.w;
        }
        __syncthreads();
#pragma unroll
        for (int i = 0; i < 2; i++) {
            int idx2 = t + i * 256;
            int n = idx2 >> 3, ck = (idx2 & 7) * 8;
            u16x8 hi, lo;
#pragma unroll
            for (int j = 0; j < 8; j++) {
                float w = Tf[ck + j][n];
                unsigned short h = f2bf(w);
                hi[j] = h; lo[j] = f2bf(w - bf2f(h));
            }
            unsigned short* dst = Wrt3 + (size_t)(n0 + n) * K3 + k0 + ck;
            *reinterpret_cast<u16x8*>(dst)            = hi;
            *reinterpret_cast<u16x8*>(dst + D_IN)     = hi;
            *reinterpret_cast<u16x8*>(dst + 2 * D_IN) = lo;
        }
    } else {
        if (t < 16) counts[t] = 0;
    }
}

// ---------------- router3 (bf16x3, 2-deep T4) + fused wtrans(W1)+wtrans(W2) ----------------
// Router blocks (256) dispatch first; wtrans blocks backfill + soak the idle
// bandwidth of this latency-bound phase (r13: saves ~20us vs serial wtrans).
__global__ __launch_bounds__(256) void k_router_wt(const unsigned short* __restrict__ xhi,
                                                   const unsigned short* __restrict__ xlo,
                                                   const unsigned short* __restrict__ wrt3,
                                                   const float* __restrict__ br,
                                                   float* __restrict__ qout,
                                                   const float* __restrict__ W1,
                                                   unsigned short* __restrict__ wt1,
                                                   const float* __restrict__ W2,
                                                   unsigned short* __restrict__ wt2) {
    __shared__ __align__(16) char smem[32768];
    int bx = blockIdx.x;
    if (bx >= 256) {
        int idx = bx - 256;
        if (idx < 8192) {          // W1: 16 kblk x 32 nblk x 16 e
            int e = idx >> 9, rem = idx & 511;
            wtrans_body(W1, wt1, D_IN, H1, e, (rem >> 5) << 6, (rem & 31) << 6, smem);
        } else {                   // W2: 32 kblk x 16 nblk x 16 e
            int i2 = idx - 8192;
            int e = i2 >> 9, rem = i2 & 511;
            wtrans_body(W2, wt2, H1, H2, e, (rem >> 4) << 6, (rem & 15) << 6, smem);
        }
        return;
    }
    unsigned short* As = (unsigned short*)smem;      // [2][4096]
    unsigned short* Bs = As + 8192;
    int nb = (bx & 3) * 64;
    int mb = (bx >> 2) * 64;

    int t    = threadIdx.x;
    int lane = t & 63;
    int w    = t >> 6;
    int wr   = (w >> 1) * 32;
    int wc   = (w & 1) * 32;

    int srow = t >> 3;
    int swz  = (t & 7) ^ (srow & 7);
    size_t aoff[2], boff[2];
#pragma unroll
    for (int i = 0; i < 2; i++) {
        int row = i * 32 + srow;
        aoff[i] = (size_t)(mb + row) * D_IN + swz * 8;
        boff[i] = (size_t)(nb + row) * K3 + swz * 8;
    }

    auto STAGE = [&](int buf, int tts) {
        const unsigned short* abase = (tts >= 16 && tts < 32) ? xlo : xhi;
        int kk = (tts & 15) * 64;
#pragma unroll
        for (int i = 0; i < 2; i++) {
            gload16(abase + aoff[i] + kk, As + buf * 4096 + (i * 32 + w * 8) * 64 + lane * 8);
            gload16(wrt3 + boff[i] + tts * 64, Bs + buf * 4096 + (i * 32 + w * 8) * 64 + lane * 8);
        }
    };

    f32x4 acc[2][2];
#pragma unroll
    for (int mi = 0; mi < 2; mi++)
#pragma unroll
        for (int ni = 0; ni < 2; ni++) acc[mi][ni] = {0.f, 0.f, 0.f, 0.f};

    int lr  = lane & 15;
    int lkc = lane >> 4;

    constexpr int NT = K3 / 64;
    STAGE(0, 0);
    STAGE(1, 1);

    for (int tt = 0; tt < NT; tt++) {
        int cur = tt & 1;
        if (tt + 1 < NT) waitcnt_vm<4>(); else waitcnt_vm<0>();
        __builtin_amdgcn_s_barrier();
        const char* Ab = (const char*)(As + cur * 4096);
        const char* Bb = (const char*)(Bs + cur * 4096);
#pragma unroll
        for (int ks = 0; ks < 2; ks++) {
            bf16x8 a[2], b[2];
#pragma unroll
            for (int mi = 0; mi < 2; mi++) {
                int row = wr + mi * 16 + lr;
                int c   = (lkc + ks * 4) ^ (row & 7);
                a[mi] = *reinterpret_cast<const bf16x8*>(Ab + row * 128 + c * 16);
            }
#pragma unroll
            for (int ni = 0; ni < 2; ni++) {
                int row = wc + ni * 16 + lr;
                int c   = (lkc + ks * 4) ^ (row & 7);
                b[ni] = *reinterpret_cast<const bf16x8*>(Bb + row * 128 + c * 16);
            }
#pragma unroll
            for (int mi = 0; mi < 2; mi++)
#pragma unroll
                for (int ni = 0; ni < 2; ni++)
                    acc[mi][ni] = __builtin_amdgcn_mfma_f32_16x16x32_bf16(a[mi], b[ni], acc[mi][ni], 0, 0, 0);
        }
        __builtin_amdgcn_s_barrier();
        if (tt + 2 < NT) STAGE(cur, tt + 2);
    }

    int rowbase = (lane >> 4) * 4;
#pragma unroll
    for (int ni = 0; ni < 2; ni++) {
        int col = nb + wc + ni * 16 + lr;
        float bv = br[col];
#pragma unroll
        for (int mi = 0; mi < 2; mi++) {
#pragma unroll
            for (int qi = 0; qi < 4; qi++) {
                int row = mb + wr + mi * 16 + rowbase + qi;
                qout[(size_t)row * EMB + col] = acc[mi][ni][qi] + bv;
            }
        }
    }
}

// ---------------- distances, softmax, top-2 — PURE, no atomics (r13 lesson:
// in-kernel fused atomicAdd to the one-cacheline counts = ~104us of cross-XCD
// line bouncing; the separate burst k_count is ~3us) ----------------
__global__ __launch_bounds__(256) void k_router_topk(const float* __restrict__ q,
                                                     const float* __restrict__ emb,
                                                     float* __restrict__ gp,
                                                     int* __restrict__ topi,
                                                     float* __restrict__ gates) {
    int b    = blockIdx.x * 4 + (threadIdx.x >> 6);
    int lane = threadIdx.x & 63;
    int e    = lane & 15;
    int seg  = (lane >> 4) * 64;
    const float* qr = q + (size_t)b * EMB + seg;
    const float* er = emb + (size_t)e * EMB + seg;
    float d2 = 0.f;
#pragma unroll 8
    for (int i = 0; i < 64; i++) { float d = qr[i] - er[i]; d2 = fmaf(d, d, d2); }
    d2 += __shfl_xor(d2, 16);
    d2 += __shfl_xor(d2, 32);
    float s = -d2;
    float m = s;
#pragma unroll
    for (int o = 1; o < 16; o <<= 1) m = fmaxf(m, __shfl_xor(m, o));
    float ex  = __expf(s - m);
    float sum = ex;
#pragma unroll
    for (int o = 1; o < 16; o <<= 1) sum += __shfl_xor(sum, o);
    if (lane < 16) gp[(size_t)b * NEXP + lane] = ex / sum;
    float v1 = s; int i1 = e;
#pragma unroll
    for (int o = 1; o < 16; o <<= 1) {
        float ov = __shfl_xor(v1, o); int oi = __shfl_xor(i1, o);
        if (ov > v1 || (ov == v1 && oi < i1)) { v1 = ov; i1 = oi; }
    }
    float s2 = (e == i1) ? -1e30f : s;
    float v2 = s2; int i2 = e;
#pragma unroll
    for (int o = 1; o < 16; o <<= 1) {
        float ov = __shfl_xor(v2, o); int oi = __shfl_xor(i2, o);
        if (ov > v2 || (ov == v2 && oi < i2)) { v2 = ov; i2 = oi; }
    }
    if (lane == 0) {
        topi[b * 2] = i1; topi[b * 2 + 1] = i2;
        float tv  = __expf(v2 - v1);
        float inv = 1.f / (1.f + tv);
        gates[b * 2] = inv; gates[b * 2 + 1] = tv * inv;
    }
}

// ---------------- count (separate burst kernel - fast) ----------------
__global__ __launch_bounds__(256) void k_count(const int* __restrict__ topi, int* __restrict__ counts) {
    int i = blockIdx.x * 256 + threadIdx.x;
    atomicAdd(&counts[topi[i]], 1);
}

// ---------------- scan: offsets + XCD bin-packed tilemaps (r12-proven) ----------------
__global__ void k_scan(const int* __restrict__ counts, int* __restrict__ offsets,
                       int* __restrict__ cursors, int2* __restrict__ tmap256,
                       int2* __restrict__ tmap128) {
    if (threadIdx.x != 0) return;
    int off = 0;
    for (int e = 0; e < NEXP; e++) {
        offsets[e] = off; cursors[e] = off;
        off += counts[e];
    }
    for (int i = 0; i < MAX_T256; i++) tmap256[i] = make_int2(-1, 0);
    for (int i = 0; i < MAX_T128; i++) tmap128[i] = make_int2(-1, 0);
    {
        int binload[8] = {0, 0, 0, 0, 0, 0, 0, 0};
        for (int e = 0; e < NEXP; e++) {
            int rem = (counts[e] + 255) >> 8, ti = 0;
            while (rem > 0) {
                int b = 0;
                for (int q2 = 1; q2 < 8; q2++)
                    if (binload[q2] < binload[b]) b = q2;
                int space = 6 - binload[b];
                if (space <= 0) break;
                int take = (rem < space) ? rem : space;
                for (int i = 0; i < take; i++)
                    tmap256[b * 6 + binload[b] + i] = make_int2(e, (ti + i) * 256);
                binload[b] += take; ti += take; rem -= take;
            }
        }
    }
    {
        int binload[8] = {0, 0, 0, 0, 0, 0, 0, 0};
        for (int e = 0; e < NEXP; e++) {
            int rem = (counts[e] + 127) >> 7, ti = 0;
            while (rem > 0) {
                int b = 0;
                for (int q2 = 1; q2 < 8; q2++)
                    if (binload[q2] < binload[b]) b = q2;
                int space = 10 - binload[b];
                if (space <= 0) break;
                int take = (rem < space) ? rem : space;
                for (int i = 0; i < take; i++)
                    tmap128[b * 10 + binload[b] + i] = make_int2(e, (ti + i) * 128);
                binload[b] += take; ti += take; rem -= take;
            }
        }
    }
}

__global__ __launch_bounds__(256) void k_scatter(const int* __restrict__ topi, int* __restrict__ cursors,
                                                 int* __restrict__ toklist, int* __restrict__ slotof) {
    int i = blockIdx.x * 256 + threadIdx.x;
    int e = topi[i];
    int s = atomicAdd(&cursors[e], 1);
    toklist[s] = i >> 1;
    slotof[i]  = s;
}

// ---------------- standalone wtrans (W3 always; W1/W2 in fallback tier) ----------------
__global__ __launch_bounds__(256) void k_wtrans(const float* __restrict__ W,
                                                unsigned short* __restrict__ Wt,
                                                int KD, int ND) {
    __shared__ __align__(16) char smem[64 * 65 * 4];
    wtrans_body(W, Wt, KD, ND, blockIdx.z, blockIdx.y * 64, blockIdx.x * 64, smem);
}

// ---------------- grouped expert GEMM (r7 body + r12 XCD bin mapping) ----------------
template <int KD, int ND, int BM, int BN, int WM, int WN, int MODE, int MINW, int CAP>
__global__ __launch_bounds__(WM * WN * 64, MINW) void k_gemm(
    const unsigned short* __restrict__ Xin, const unsigned short* __restrict__ Wt,
    const float* __restrict__ bg, unsigned short* __restrict__ Hout,
    float* __restrict__ Oout, const int* __restrict__ counts,
    const int* __restrict__ offsets, const int* __restrict__ toklist,
    const int2* __restrict__ tmap) {
    constexpr int THREADS = WM * WN * 64;
    constexpr int FM = BM / (WM * 16);
    constexpr int FN = BN / (WN * 16);
    constexpr int A_ISS = BM * 8 / THREADS;
    constexpr int B_ISS = BN * 8 / THREADS;
    constexpr int RPI = THREADS / 8;
    constexpr int SL  = A_ISS + B_ISS;

    int id  = blockIdx.x;
    int bin = id & 7;
    int j   = id >> 3;
    int y   = bin * CAP + j % CAP;
    int xnb = j / CAP;

    int2 tm = tmap[y];
    int e = tm.x;
    if (e < 0) return;
    int base = tm.y;
    int n_e  = counts[e];
    int off  = offsets[e];
    int n0   = xnb * BN;

    __shared__ __align__(16) unsigned short As[2][BM * 64];
    __shared__ __align__(16) unsigned short Bs[2][BN * 64];

    int t    = threadIdx.x;
    int lane = t & 63;
    int w    = t >> 6;
    int wm   = w / WN;
    int wn   = w % WN;

    int srow  = t >> 3;
    int chunk = t & 7;
    const unsigned short* asrc[A_ISS];
    const unsigned short* bsrc[B_ISS];
#pragma unroll
    for (int i = 0; i < A_ISS; i++) {
        int row = i * RPI + srow;
        int swz = chunk ^ (row & 7);
        int g   = base + row;
        size_t arow;
        if (MODE == 0) {
            int gg = (g < n_e) ? g : (n_e - 1);
            arow = (size_t)toklist[off + gg];
        } else {
            arow = (size_t)(off + g);
        }
        asrc[i] = Xin + arow * KD + swz * 8;
    }
#pragma unroll
    for (int i = 0; i < B_ISS; i++) {
        int row = i * RPI + srow;
        int swz = chunk ^ (row & 7);
        bsrc[i] = Wt + ((size_t)e * ND + n0 + row) * KD + swz * 8;
    }

    auto STAGE = [&](int buf, int kt) {
#pragma unroll
        for (int i = 0; i < A_ISS; i++)
            gload16(asrc[i] + kt, &As[buf][(i * RPI + w * 8) * 64] + lane * 8);
#pragma unroll
        for (int i = 0; i < B_ISS; i++)
            gload16(bsrc[i] + kt, &Bs[buf][(i * RPI + w * 8) * 64] + lane * 8);
    };

    f32x4 acc[FM][FN];
#pragma unroll
    for (int mi = 0; mi < FM; mi++)
#pragma unroll
        for (int ni = 0; ni < FN; ni++) acc[mi][ni] = {0.f, 0.f, 0.f, 0.f};

    int lr  = lane & 15;
    int lkc = lane >> 4;

    constexpr int NT = KD / 64;
    STAGE(0, 0);
    STAGE(1, 64);

    for (int tt = 0; tt < NT; tt++) {
        int cur = tt & 1;
        if (tt + 1 < NT) waitcnt_vm<SL>(); else waitcnt_vm<0>();
        __builtin_amdgcn_s_barrier();
        const char* Ab = (const char*)As[cur];
        const char* Bb = (const char*)Bs[cur];
#pragma unroll
        for (int ks = 0; ks < 2; ks++) {
            bf16x8 b[FN];
#pragma unroll
            for (int ni = 0; ni < FN; ni++) {
                int row = wn * (BN / WN) + ni * 16 + lr;
                int c   = (lkc + ks * 4) ^ (row & 7);
                b[ni] = *reinterpret_cast<const bf16x8*>(Bb + row * 128 + c * 16);
            }
            bf16x8 a[FM];
#pragma unroll
            for (int mi = 0; mi < FM; mi++) {
                int row = wm * (BM / WM) + mi * 16 + lr;
                int c   = (lkc + ks * 4) ^ (row & 7);
                a[mi] = *reinterpret_cast<const bf16x8*>(Ab + row * 128 + c * 16);
            }
#pragma unroll
            for (int mi = 0; mi < FM; mi++)
#pragma unroll
                for (int ni = 0; ni < FN; ni++)
                    acc[mi][ni] = __builtin_amdgcn_mfma_f32_16x16x32_bf16(a[mi], b[ni], acc[mi][ni], 0, 0, 0);
        }
        __builtin_amdgcn_s_barrier();
        if (tt + 2 < NT) STAGE(cur, (tt + 2) * 64);
    }

    int rowbase = (lane >> 4) * 4;
#pragma unroll
    for (int ni = 0; ni < FN; ni++) {
        int col = n0 + wn * (BN / WN) + ni * 16 + lr;
        float bv = bg[(size_t)e * ND + col];
#pragma unroll
        for (int mi = 0; mi < FM; mi++) {
#pragma unroll
            for (int qi = 0; qi < 4; qi++) {
                int g = base + wm * (BM / WM) + mi * 16 + rowbase + qi;
                if (g < n_e) {
                    float v = acc[mi][ni][qi] + bv;
                    if (MODE == 2) {
                        Oout[(size_t)(off + g) * ND + col] = v;
                    } else {
                        v = fmaxf(v, 0.f);
                        Hout[(size_t)(off + g) * ND + col] = f2bf(v);
                    }
                }
            }
        }
    }
}

// ---------------- final combine ----------------
__global__ __launch_bounds__(128) void k_combine(const float* __restrict__ osl,
                                                 const float* __restrict__ gates,
                                                 const int* __restrict__ slotof,
                                                 float* __restrict__ outf) {
    int b = blockIdx.x;
    int j = threadIdx.x;
    int s0 = slotof[b * 2], s1 = slotof[b * 2 + 1];
    float g0 = gates[b * 2], g1 = gates[b * 2 + 1];
    float4 o0 = reinterpret_cast<const float4*>(osl + (size_t)s0 * OUTD)[j];
    float4 o1 = reinterpret_cast<const float4*>(osl + (size_t)s1 * OUTD)[j];
    float4 r;
    r.x = g0 * o0.x + g1 * o1.x;
    r.y = g0 * o0.y + g1 * o1.y;
    r.z = g0 * o0.z + g1 * o1.z;
    r.w = g0 * o0.w + g1 * o1.w;
    reinterpret_cast<float4*>(outf + (size_t)b * OUTD)[j] = r;
}

extern "C" void kernel_launch(void* const* d_in, const int* in_sizes, int n_in,
                              void* d_out, int out_size, void* d_ws, size_t ws_size,
                              hipStream_t stream) {
    const float* x   = (const float*)d_in[0];
    const float* Wr  = (const float*)d_in[1];
    const float* br  = (const float*)d_in[2];
    const float* emb = (const float*)d_in[3];
    const float* W1  = (const float*)d_in[4];
    const float* b1  = (const float*)d_in[5];
    const float* W2  = (const float*)d_in[6];
    const float* b2  = (const float*)d_in[7];
    const float* W3  = (const float*)d_in[8];
    const float* b3  = (const float*)d_in[9];

    float* out_final = (float*)d_out;
    float* out_q     = out_final + (size_t)BATCH * OUTD;
    float* out_gp    = out_q + (size_t)BATCH * EMB;

    char* ws = (char*)d_ws;
    unsigned short* xb  = (unsigned short*)(ws + WS_XB);
    unsigned short* xlo = (unsigned short*)(ws + WS_XLO);
    unsigned short* h1  = (unsigned short*)(ws + WS_H1);
    unsigned short* h2  = (unsigned short*)(ws + WS_H2);
    float* osl    = (float*)(ws + WS_OSL);
    int*   topi   = (int*)(ws + WS_TOPI);
    float* gates  = (float*)(ws + WS_GATES);
    int*   slotof = (int*)(ws + WS_SLOTOF);
    int*   toklist= (int*)(ws + WS_TOKL);
    int*   counts = (int*)(ws + WS_CNT);
    int*   offsets= counts + 16;
    int*   cursors= counts + 32;
    int2*  tmap256= (int2*)(ws + WS_TMAP256);
    int2*  tmap128= (int2*)(ws + WS_TMAP128);
    unsigned short* wrt3 = (unsigned short*)(ws + WS_WR3);
    unsigned short* wtA  = (unsigned short*)(ws + WS_WT);
    unsigned short* wtB  = (unsigned short*)(ws + WS_WTB);

    const bool t2 = (ws_size >= NEED2);

    k_prep<<<4161, 256, 0, stream>>>(x, xb, xlo, Wr, wrt3, counts);

    if (t2) {
        k_router_wt<<<256 + 8192 + 8192, 256, 0, stream>>>(
            xb, xlo, wrt3, br, out_q, W1, wtA, W2, wtB);
    } else {
        k_router_wt<<<256, 256, 0, stream>>>(
            xb, xlo, wrt3, br, out_q, nullptr, nullptr, nullptr, nullptr);
    }

    k_router_topk<<<BATCH / 4, 256, 0, stream>>>(out_q, emb, out_gp, topi, gates);
    k_count<<<SLOTS / 256, 256, 0, stream>>>(topi, counts);
    k_scan<<<1, 64, 0, stream>>>(counts, offsets, cursors, tmap256, tmap128);
    k_scatter<<<SLOTS / 256, 256, 0, stream>>>(topi, cursors, toklist, slotof);

    if (!t2) k_wtrans<<<dim3(H1 / 64, D_IN / 64, NEXP), 256, 0, stream>>>(W1, wtA, D_IN, H1);
    k_gemm<D_IN, H1, 256, 256, 2, 4, 0, 1, 6><<<(H1 / 256) * 48, 512, 0, stream>>>(
        xb, wtA, b1, h1, nullptr, counts, offsets, toklist, tmap256);

    if (!t2) k_wtrans<<<dim3(H2 / 64, H1 / 64, NEXP), 256, 0, stream>>>(W2, wtA, H1, H2);
    k_gemm<H1, H2, 256, 256, 2, 4, 1, 1, 6><<<(H2 / 256) * 48, 512, 0, stream>>>(
        h1, t2 ? wtB : wtA, b2, h2, nullptr, counts, offsets, toklist, tmap256);

    k_wtrans<<<dim3(OUTD / 64, H2 / 64, NEXP), 256, 0, stream>>>(W3, wtA, H2, OUTD);
    k_gemm<H2, OUTD, 128, 128, 2, 2, 2, 2, 10><<<(OUTD / 128) * 80, 256, 0, stream>>>(
        h2, wtA, b3, nullptr, osl, counts, offsets, toklist, tmap128);

    k_combine<<<BATCH, 128, 0, stream>>>(osl, gates, slotof, out_final);
}